// Round 1
// baseline (414.360 us; speedup 1.0000x reference)
//
#include <hip/hip_runtime.h>

#define NN 100000
#define NE 3200000
#define CH 8192                        // edges per chunk
#define NCB ((NE + CH - 1) / CH)       // 391 chunks
#define ITER (CH / 256)                // 32
#define NBK ((NN + 63) >> 6)           // 1563 dst-buckets of 64 nodes
#define CAP 2560                       // payload capacity per sort round (5*512)

// Detect label storage: int32 (harness-normalized) vs raw uint8 bool.
__global__ void kdetect(const unsigned char* __restrict__ lab8, int* __restrict__ flags) {
  __shared__ int tmp[256];
  int t = threadIdx.x;
  int s = 0;
  for (int i = t; i < 25000; i += 256) s += lab8[4 * i + 1];
  tmp[t] = s;
  __syncthreads();
  for (int d = 128; d > 0; d >>= 1) { if (t < d) tmp[t] += tmp[t + d]; __syncthreads(); }
  if (t == 0) flags[0] = (tmp[0] != 0) ? 1 : 0;
}

__global__ void klab(const void* __restrict__ lab, const int* __restrict__ flags,
                     int* __restrict__ labN) {
  int n = blockIdx.x * 256 + threadIdx.x;
  if (n >= NN) return;
  int v;
  if (flags[0]) v = ((const unsigned char*)lab)[n];
  else          v = ((const int*)lab)[n];
  labN[n] = (v != 0) ? 1 : 0;
}

// c01 = W_edge @ att_edge
__global__ void kc01(const float* __restrict__ We, const float* __restrict__ ae,
                     float* __restrict__ c01) {
  if (threadIdx.x == 0) {
    float c0 = 0.f, c1 = 0.f;
    for (int k = 0; k < 16; k++) { c0 += We[k] * ae[k]; c1 += We[16 + k] * ae[k]; }
    c01[0] = c0; c01[1] = c1;
  }
}

// a_src = (x@Wg)@att_src ; a_dst = (x@Wg)@att_dst  (h not materialized)
__global__ void knodeA(const float* __restrict__ x, const float* __restrict__ Wg,
                       const float* __restrict__ atts, const float* __restrict__ attd,
                       float* __restrict__ a_src, float* __restrict__ a_dst) {
  int n = blockIdx.x * 256 + threadIdx.x;
  if (n >= NN) return;
  float xi[5];
#pragma unroll
  for (int i = 0; i < 5; i++) xi[i] = x[n * 5 + i];
  float asum = 0.f, dsum = 0.f;
#pragma unroll
  for (int k = 0; k < 16; k++) {
    float acc = 0.f;
#pragma unroll
    for (int i = 0; i < 5; i++) acc += xi[i] * Wg[i * 16 + k];
    asum += acc * atts[k];
    dsum += acc * attd[k];
  }
  a_src[n] = asum; a_dst[n] = dsum;
}

// Pass 1: per-chunk bucket histogram + per-chunk valid-edge count.
__global__ __launch_bounds__(256) void khist(const int* __restrict__ src,
                                             const int* __restrict__ dst,
                                             const int* __restrict__ labN,
                                             int* __restrict__ blkcnt,
                                             int* __restrict__ cntc) {
  __shared__ int hist[NBK];
  __shared__ int vsum;
  int tid = threadIdx.x, b = blockIdx.x;
  for (int i = tid; i < NBK; i += 256) hist[i] = 0;
  if (tid == 0) vsum = 0;
  __syncthreads();
  int wsum = 0;
  for (int it = 0; it < ITER; ++it) {
    int e = b * CH + it * 256 + tid;
    int v = 0;
    if (e < NE) {
      int s = src[e], d = dst[e];
      atomicAdd(&hist[d >> 6], 1);
      v = labN[s] & labN[d];
    }
    unsigned long long m = __ballot(v != 0);
    wsum += __popcll(m);
  }
  if ((tid & 63) == 0) atomicAdd(&vsum, wsum);
  __syncthreads();
  for (int i = tid; i < NBK; i += 256) blkcnt[i * NCB + b] = hist[i];
  if (tid == 0) cntc[b] = vsum;
}

// Pass 2a: per-bucket exclusive scan over chunks (row of blkcnt), totals out.
__global__ __launch_bounds__(256) void kscanb(int* __restrict__ blkcnt,
                                              int* __restrict__ total) {
  __shared__ int a[512];
  int row = blockIdx.x, t = threadIdx.x;
  int* p = blkcnt + row * NCB;
  int o0 = (t < NCB) ? p[t] : 0;
  int o1 = (t + 256 < NCB) ? p[t + 256] : 0;
  a[t] = o0; a[t + 256] = o1;
  __syncthreads();
  for (int d = 1; d < 512; d <<= 1) {
    int x0 = (t >= d) ? a[t - d] : 0;
    int x1 = (t + 256 >= d) ? a[t + 256 - d] : 0;
    __syncthreads();
    a[t] += x0; a[t + 256] += x1;
    __syncthreads();
  }
  if (t < NCB) p[t] = a[t] - o0;
  if (t + 256 < NCB) p[t + 256] = a[t + 256] - o1;
  if (t == 0) total[row] = a[NCB - 1];
}

// generic single-block exclusive scan; also writes off[nb] = grand total
__global__ void kscan(const int* __restrict__ cnt, int* __restrict__ off, int nb) {
  __shared__ int tmp[256];
  __shared__ int carry;
  int t = threadIdx.x;
  if (t == 0) carry = 0;
  __syncthreads();
  for (int base = 0; base < nb; base += 256) {
    int i = base + t;
    int v = (i < nb) ? cnt[i] : 0;
    tmp[t] = v;
    __syncthreads();
    for (int d = 1; d < 256; d <<= 1) {
      int add = (t >= d) ? tmp[t - d] : 0;
      __syncthreads();
      tmp[t] += add;
      __syncthreads();
    }
    if (i < nb) off[i] = carry + tmp[t] - v;
    __syncthreads();
    if (t == 0) carry += tmp[255];
    __syncthreads();
  }
  if (t == 0) off[nb] = carry;
}

// Pass 3: compute ex, scatter (src,ldst,ex) to bins via LDS cursors; ALSO the
// ordered output compaction (out src/dst + compacted edge_attr) fused in.
__global__ __launch_bounds__(256) void kscat(
    const int* __restrict__ src, const int* __restrict__ dst,
    const float* __restrict__ eattr, const int* __restrict__ labN,
    const float* __restrict__ a_src, const float* __restrict__ a_dst,
    const float* __restrict__ c01, const int* __restrict__ bucket_base,
    const int* __restrict__ blkcnt, const int* __restrict__ offc,
    uint2* __restrict__ bins, float* __restrict__ out,
    float2* __restrict__ eat2, int NV) {
  __shared__ int cur[NBK];
  __shared__ int wc[4];
  __shared__ int lbase;
  int b = blockIdx.x, tid = threadIdx.x;
  for (int i = tid; i < NBK; i += 256) cur[i] = bucket_base[i] + blkcnt[i * NCB + b];
  if (tid == 0) lbase = offc[b];
  float c0 = c01[0], c1 = c01[1];
  __syncthreads();
  int lane = tid & 63, wid = tid >> 6;
  for (int it = 0; it < ITER; ++it) {
    int e = b * CH + it * 256 + tid;
    int v = 0, s = 0, d = 0;
    float2 ea;
    if (e < NE) {
      s = src[e]; d = dst[e];
      ea = ((const float2*)eattr)[e];
      float al = a_src[s] + a_dst[d] + ea.x * c0 + ea.y * c1;
      al = (al > 0.f) ? al : 0.2f * al;
      float exv = __expf(al);
      int pos = atomicAdd(&cur[d >> 6], 1);
      uint2 pl;
      pl.x = ((unsigned)s << 6) | (unsigned)(d & 63);
      pl.y = __float_as_uint(exv);
      bins[pos] = pl;
      v = labN[s] & labN[d];
    }
    unsigned long long m = __ballot(v != 0);
    if (lane == 0) wc[wid] = __popcll(m);
    __syncthreads();
    int pre = 0;
    for (int i = 0; i < wid; i++) pre += wc[i];
    pre += __popcll(m & ((1ull << lane) - 1ull));
    if (v) {
      int p = lbase + pre;
      if (p < NV) {
        out[p] = (float)s;
        out[NV + p] = (float)d;
        eat2[p] = ea;
      }
    }
    __syncthreads();
    if (tid == 0) lbase += wc[0] + wc[1] + wc[2] + wc[3];
  }
}

// Pass 4: one block per 64-node bucket. Counting-sort the bucket's payloads by
// local node in LDS (int atomics only), then walk each node's contiguous run
// with 16 lanes/node accumulating in REGISTERS (no f32 atomics, no shuffles;
// x[s] loads are broadcast within each 16-lane group). Fused norm+bias+relu.
__global__ __launch_bounds__(512) void kagg(
    const uint2* __restrict__ bins, const int* __restrict__ bucket_base,
    const float* __restrict__ x, const float* __restrict__ Wg,
    const float* __restrict__ bg, float* __restrict__ xh) {
  __shared__ uint2 pay[CAP];
  __shared__ int cnt[64], inc[64], cur[64];
  __shared__ float sWg[80], sbg[16];
  int k = blockIdx.x, tid = threadIdx.x;
  if (tid < 80) sWg[tid] = Wg[tid];
  else if (tid < 96) sbg[tid - 80] = bg[tid - 80];
  int start = bucket_base[k], end = bucket_base[k + 1];
  int node0 = k << 6;
  int c = tid & 15, g = tid >> 4;     // g: 0..31
  __syncthreads();
  float w0 = sWg[c], w1 = sWg[16 + c], w2 = sWg[32 + c], w3 = sWg[48 + c], w4 = sWg[64 + c];
  float acc[2] = {0.f, 0.f}, den[2] = {0.f, 0.f};
  for (int cb = start; cb < end; cb += CAP) {        // single round in practice
    int n = min(end - cb, CAP);
    if (tid < 64) cnt[tid] = 0;
    __syncthreads();
    uint2 st0, st1, st2, st3, st4;                   // register-staged payloads
    {
      int i;
      i = tid;          if (i < n) { st0 = bins[cb + i]; atomicAdd(&cnt[st0.x & 63], 1); }
      i = tid + 512;    if (i < n) { st1 = bins[cb + i]; atomicAdd(&cnt[st1.x & 63], 1); }
      i = tid + 1024;   if (i < n) { st2 = bins[cb + i]; atomicAdd(&cnt[st2.x & 63], 1); }
      i = tid + 1536;   if (i < n) { st3 = bins[cb + i]; atomicAdd(&cnt[st3.x & 63], 1); }
      i = tid + 2048;   if (i < n) { st4 = bins[cb + i]; atomicAdd(&cnt[st4.x & 63], 1); }
    }
    __syncthreads();
    if (tid < 64) inc[tid] = cnt[tid];
    __syncthreads();
    for (int d = 1; d < 64; d <<= 1) {
      int v = 0;
      if (tid >= d && tid < 64) v = inc[tid - d];
      __syncthreads();
      if (tid < 64) inc[tid] += v;
      __syncthreads();
    }
    if (tid < 64) cur[tid] = inc[tid] - cnt[tid];
    __syncthreads();
    {
      int i;
      i = tid;          if (i < n) pay[atomicAdd(&cur[st0.x & 63], 1)] = st0;
      i = tid + 512;    if (i < n) pay[atomicAdd(&cur[st1.x & 63], 1)] = st1;
      i = tid + 1024;   if (i < n) pay[atomicAdd(&cur[st2.x & 63], 1)] = st2;
      i = tid + 1536;   if (i < n) pay[atomicAdd(&cur[st3.x & 63], 1)] = st3;
      i = tid + 2048;   if (i < n) pay[atomicAdd(&cur[st4.x & 63], 1)] = st4;
    }
    __syncthreads();
#pragma unroll
    for (int p = 0; p < 2; ++p) {
      int nd = p * 32 + g;
      int re = inc[nd], rs = re - cnt[nd];
      float a = 0.f, ds = 0.f;
      for (int idx = rs; idx < re; ++idx) {
        uint2 pl = pay[idx];                         // broadcast ds_read_b64
        int s = (int)(pl.x >> 6);
        float exv = __uint_as_float(pl.y);
        const float* xp = x + s * 5;                 // broadcast within group
        float h = xp[0] * w0 + xp[1] * w1 + xp[2] * w2 + xp[3] * w3 + xp[4] * w4;
        a += h * exv;
        ds += exv;
      }
      acc[p] += a; den[p] += ds;
    }
    __syncthreads();
  }
#pragma unroll
  for (int p = 0; p < 2; ++p) {
    int node = node0 + p * 32 + g;
    if (node < NN) {
      float dn = fmaxf(den[p], 1e-30f);
      float v = acc[p] / dn + sbg[c];
      xh[node * 16 + c] = (v > 0.f) ? v : 0.f;
    }
  }
}

// NEW Pass 5a: per-node MLP-layer-1 partials.
//   u[n][0:64] = b1 + xh[n] @ W1[rows 0:16]    (src-side contribution)
//   v[n][0:64] =      xh[n] @ W1[rows 18:34]   (dst-side contribution)
// 16 threads per node, each owns a contiguous float4 of j -> fully coalesced
// 1024B stores per wave. 128 FMA/thread; weights broadcast from LDS.
__global__ __launch_bounds__(256) void kprep(
    const float* __restrict__ xh, const float* __restrict__ W1,
    const float* __restrict__ b1, float* __restrict__ u, float* __restrict__ v) {
  __shared__ float sW1[34 * 64];
  __shared__ float sb1[64];
  for (int i = threadIdx.x; i < 34 * 64; i += 256) sW1[i] = W1[i];
  if (threadIdx.x < 64) sb1[threadIdx.x] = b1[threadIdx.x];
  __syncthreads();
  int t = threadIdx.x;
  int node = blockIdx.x * 16 + (t >> 4);
  if (node >= NN) return;
  int jq = (t & 15) * 4;
  float xf[16];
  const float4* xp = (const float4*)(xh + node * 16);
#pragma unroll
  for (int q = 0; q < 4; q++) {
    float4 tv = xp[q];
    xf[q * 4 + 0] = tv.x; xf[q * 4 + 1] = tv.y;
    xf[q * 4 + 2] = tv.z; xf[q * 4 + 3] = tv.w;
  }
  float uu[4], vv[4];
#pragma unroll
  for (int j = 0; j < 4; j++) { uu[j] = sb1[jq + j]; vv[j] = 0.f; }
#pragma unroll
  for (int i = 0; i < 16; i++) {
    float f = xf[i];
    const float* wu = sW1 + i * 64 + jq;
    const float* wv = sW1 + (18 + i) * 64 + jq;
#pragma unroll
    for (int j = 0; j < 4; j++) {
      uu[j] += f * wu[j];
      vv[j] += f * wv[j];
    }
  }
  *(float4*)(u + (size_t)node * 64 + jq) = make_float4(uu[0], uu[1], uu[2], uu[3]);
  *(float4*)(v + (size_t)node * 64 + jq) = make_float4(vv[0], vv[1], vv[2], vv[3]);
}

// NEW Pass 5b: per-edge finish. hidden = u[s] + v[d] + ea.x*W1[16] + ea.y*W1[17]
// -> relu -> @W2 -> sigmoid. ~384 VALU ops + 512B gather per edge (was ~2300
// FMAs + 544 LDS b128 reads). u/v working set = 51MB, L3-resident.
__global__ __launch_bounds__(256) void kmlp2(
    const float2* __restrict__ eat2, const float* __restrict__ u,
    const float* __restrict__ v, const float* __restrict__ W1,
    const float* __restrict__ W2, const float* __restrict__ b2,
    float* __restrict__ out, int NV) {
  __shared__ float sE[128];   // W1 rows 16 (ea.x) and 17 (ea.y)
  __shared__ float sW2[128];
  __shared__ float sb2[2];
  if (threadIdx.x < 128) sE[threadIdx.x] = W1[16 * 64 + threadIdx.x];
  else sW2[threadIdx.x - 128] = W2[threadIdx.x - 128];
  if (threadIdx.x < 2) sb2[threadIdx.x] = b2[threadIdx.x];
  __syncthreads();
  int p = blockIdx.x * 256 + threadIdx.x;
  if (p >= NV) return;
  int s = (int)out[p];
  int d = (int)out[NV + p];
  float2 ea = eat2[p];
  const float4* up = (const float4*)(u + (size_t)s * 64);
  const float4* vp = (const float4*)(v + (size_t)d * 64);
  float o0 = sb2[0], o1 = sb2[1];
#pragma unroll
  for (int q = 0; q < 16; q++) {
    float4 a = up[q];
    float4 b = vp[q];
    const float* e0 = sE + q * 4;
    const float* e1 = sE + 64 + q * 4;
    float h0 = a.x + b.x + ea.x * e0[0] + ea.y * e1[0];
    float h1 = a.y + b.y + ea.x * e0[1] + ea.y * e1[1];
    float h2 = a.z + b.z + ea.x * e0[2] + ea.y * e1[2];
    float h3 = a.w + b.w + ea.x * e0[3] + ea.y * e1[3];
    h0 = fmaxf(h0, 0.f); h1 = fmaxf(h1, 0.f);
    h2 = fmaxf(h2, 0.f); h3 = fmaxf(h3, 0.f);
    const float* w2p = sW2 + q * 8;
    o0 += h0 * w2p[0] + h1 * w2p[2] + h2 * w2p[4] + h3 * w2p[6];
    o1 += h0 * w2p[1] + h1 * w2p[3] + h2 * w2p[5] + h3 * w2p[7];
  }
  out[2 * NV + 2 * p + 0] = 1.f / (1.f + __expf(-o0));
  out[2 * NV + 2 * p + 1] = 1.f / (1.f + __expf(-o1));
}

static inline size_t al64(size_t v) { return (v + 63) & ~(size_t)63; }

extern "C" void kernel_launch(void* const* d_in, const int* in_sizes, int n_in,
                              void* d_out, int out_size, void* d_ws, size_t ws_size,
                              hipStream_t stream) {
  const float* x     = (const float*)d_in[0];
  const int*   edges = (const int*)d_in[1];
  const float* eattr = (const float*)d_in[2];
  const void*  labels= d_in[3];
  const float* Wg    = (const float*)d_in[4];
  const float* atts  = (const float*)d_in[5];
  const float* attd  = (const float*)d_in[6];
  const float* We    = (const float*)d_in[7];
  const float* atte  = (const float*)d_in[8];
  const float* bg    = (const float*)d_in[9];
  const float* W1    = (const float*)d_in[10];
  const float* b1    = (const float*)d_in[11];
  const float* W2    = (const float*)d_in[12];
  const float* b2    = (const float*)d_in[13];
  float* out = (float*)d_out;
  const int NV = out_size / 4;
  const int* src = edges;
  const int* dst = edges + NE;

  char* w = (char*)d_ws;
  float* xh    = (float*)w;   w += al64((size_t)NN * 64);
  uint2* bins  = (uint2*)w;   w += al64((size_t)NE * 8);
  float2* eat2 = (float2*)w;  w += al64((size_t)NV * 8);
  float* a_src = (float*)w;   w += al64((size_t)NN * 4);
  float* a_dst = (float*)w;   w += al64((size_t)NN * 4);
  int* labN    = (int*)w;     w += al64((size_t)NN * 4);
  int* blkcnt  = (int*)w;     w += al64((size_t)NBK * NCB * 4);
  int* total   = (int*)w;     w += al64((size_t)NBK * 4);
  int* bb      = (int*)w;     w += al64((size_t)(NBK + 1) * 4);
  int* cntc    = (int*)w;     w += al64((size_t)NCB * 4);
  int* offc    = (int*)w;     w += al64((size_t)(NCB + 1) * 4);
  float* c01   = (float*)w;   w += 64;
  int* flags   = (int*)w;     w += 64;
  // u reuses bins (dead after kagg; NE*8 == NN*64*4 bytes exactly). v is new.
  float* uvec  = (float*)bins;
  float* vvec  = (float*)w;   w += al64((size_t)NN * 256);

  kdetect<<<1, 256, 0, stream>>>((const unsigned char*)labels, flags);
  klab<<<(NN + 255) / 256, 256, 0, stream>>>(labels, flags, labN);
  kc01<<<1, 64, 0, stream>>>(We, atte, c01);
  knodeA<<<(NN + 255) / 256, 256, 0, stream>>>(x, Wg, atts, attd, a_src, a_dst);
  khist<<<NCB, 256, 0, stream>>>(src, dst, labN, blkcnt, cntc);
  kscanb<<<NBK, 256, 0, stream>>>(blkcnt, total);
  kscan<<<1, 256, 0, stream>>>(total, bb, NBK);
  kscan<<<1, 256, 0, stream>>>(cntc, offc, NCB);
  kscat<<<NCB, 256, 0, stream>>>(src, dst, eattr, labN, a_src, a_dst, c01, bb, blkcnt,
                                 offc, bins, out, eat2, NV);
  kagg<<<NBK, 512, 0, stream>>>(bins, bb, x, Wg, bg, xh);
  kprep<<<(NN + 15) / 16, 256, 0, stream>>>(xh, W1, b1, uvec, vvec);
  if (NV > 0)
    kmlp2<<<(NV + 255) / 256, 256, 0, stream>>>(eat2, uvec, vvec, W1, W2, b2, out, NV);
}

// Round 2
// 393.248 us; speedup vs baseline: 1.0537x; 1.0537x over previous
//
#include <hip/hip_runtime.h>

#define NN 100000
#define NE 3200000
#define CH 8192                        // edges per chunk
#define NCB ((NE + CH - 1) / CH)       // 391 chunks
#define ITER (CH / 256)                // 32
#define NBK ((NN + 63) >> 6)           // 1563 dst-buckets of 64 nodes
#define CAP 2560                       // payload capacity per sort round (5*512)

// Detect label storage: int32 (harness-normalized) vs raw uint8 bool.
__global__ void kdetect(const unsigned char* __restrict__ lab8, int* __restrict__ flags) {
  __shared__ int tmp[256];
  int t = threadIdx.x;
  int s = 0;
  for (int i = t; i < 25000; i += 256) s += lab8[4 * i + 1];
  tmp[t] = s;
  __syncthreads();
  for (int d = 128; d > 0; d >>= 1) { if (t < d) tmp[t] += tmp[t + d]; __syncthreads(); }
  if (t == 0) flags[0] = (tmp[0] != 0) ? 1 : 0;
}

__global__ void klab(const void* __restrict__ lab, const int* __restrict__ flags,
                     int* __restrict__ labN) {
  int n = blockIdx.x * 256 + threadIdx.x;
  if (n >= NN) return;
  int v;
  if (flags[0]) v = ((const unsigned char*)lab)[n];
  else          v = ((const int*)lab)[n];
  labN[n] = (v != 0) ? 1 : 0;
}

// c01 = W_edge @ att_edge
__global__ void kc01(const float* __restrict__ We, const float* __restrict__ ae,
                     float* __restrict__ c01) {
  if (threadIdx.x == 0) {
    float c0 = 0.f, c1 = 0.f;
    for (int k = 0; k < 16; k++) { c0 += We[k] * ae[k]; c1 += We[16 + k] * ae[k]; }
    c01[0] = c0; c01[1] = c1;
  }
}

// a_src = (x@Wg)@att_src ; a_dst = (x@Wg)@att_dst  (h not materialized)
__global__ void knodeA(const float* __restrict__ x, const float* __restrict__ Wg,
                       const float* __restrict__ atts, const float* __restrict__ attd,
                       float* __restrict__ a_src, float* __restrict__ a_dst) {
  int n = blockIdx.x * 256 + threadIdx.x;
  if (n >= NN) return;
  float xi[5];
#pragma unroll
  for (int i = 0; i < 5; i++) xi[i] = x[n * 5 + i];
  float asum = 0.f, dsum = 0.f;
#pragma unroll
  for (int k = 0; k < 16; k++) {
    float acc = 0.f;
#pragma unroll
    for (int i = 0; i < 5; i++) acc += xi[i] * Wg[i * 16 + k];
    asum += acc * atts[k];
    dsum += acc * attd[k];
  }
  a_src[n] = asum; a_dst[n] = dsum;
}

// Pass 1: per-chunk bucket histogram + per-chunk valid-edge count.
__global__ __launch_bounds__(256) void khist(const int* __restrict__ src,
                                             const int* __restrict__ dst,
                                             const int* __restrict__ labN,
                                             int* __restrict__ blkcnt,
                                             int* __restrict__ cntc) {
  __shared__ int hist[NBK];
  __shared__ int vsum;
  int tid = threadIdx.x, b = blockIdx.x;
  for (int i = tid; i < NBK; i += 256) hist[i] = 0;
  if (tid == 0) vsum = 0;
  __syncthreads();
  int wsum = 0;
  for (int it = 0; it < ITER; ++it) {
    int e = b * CH + it * 256 + tid;
    int v = 0;
    if (e < NE) {
      int s = src[e], d = dst[e];
      atomicAdd(&hist[d >> 6], 1);
      v = labN[s] & labN[d];
    }
    unsigned long long m = __ballot(v != 0);
    wsum += __popcll(m);
  }
  if ((tid & 63) == 0) atomicAdd(&vsum, wsum);
  __syncthreads();
  for (int i = tid; i < NBK; i += 256) blkcnt[i * NCB + b] = hist[i];
  if (tid == 0) cntc[b] = vsum;
}

// Pass 2a: per-bucket exclusive scan over chunks (row of blkcnt), totals out.
__global__ __launch_bounds__(256) void kscanb(int* __restrict__ blkcnt,
                                              int* __restrict__ total) {
  __shared__ int a[512];
  int row = blockIdx.x, t = threadIdx.x;
  int* p = blkcnt + row * NCB;
  int o0 = (t < NCB) ? p[t] : 0;
  int o1 = (t + 256 < NCB) ? p[t + 256] : 0;
  a[t] = o0; a[t + 256] = o1;
  __syncthreads();
  for (int d = 1; d < 512; d <<= 1) {
    int x0 = (t >= d) ? a[t - d] : 0;
    int x1 = (t + 256 >= d) ? a[t + 256 - d] : 0;
    __syncthreads();
    a[t] += x0; a[t + 256] += x1;
    __syncthreads();
  }
  if (t < NCB) p[t] = a[t] - o0;
  if (t + 256 < NCB) p[t + 256] = a[t + 256] - o1;
  if (t == 0) total[row] = a[NCB - 1];
}

// generic single-block exclusive scan; also writes off[nb] = grand total
__global__ void kscan(const int* __restrict__ cnt, int* __restrict__ off, int nb) {
  __shared__ int tmp[256];
  __shared__ int carry;
  int t = threadIdx.x;
  if (t == 0) carry = 0;
  __syncthreads();
  for (int base = 0; base < nb; base += 256) {
    int i = base + t;
    int v = (i < nb) ? cnt[i] : 0;
    tmp[t] = v;
    __syncthreads();
    for (int d = 1; d < 256; d <<= 1) {
      int add = (t >= d) ? tmp[t - d] : 0;
      __syncthreads();
      tmp[t] += add;
      __syncthreads();
    }
    if (i < nb) off[i] = carry + tmp[t] - v;
    __syncthreads();
    if (t == 0) carry += tmp[255];
    __syncthreads();
  }
  if (t == 0) off[nb] = carry;
}

// Pass 3: compute ex, scatter (src,ldst,ex) to bins via LDS cursors; ALSO the
// ordered output compaction (out src/dst + compacted edge_attr) fused in.
__global__ __launch_bounds__(256) void kscat(
    const int* __restrict__ src, const int* __restrict__ dst,
    const float* __restrict__ eattr, const int* __restrict__ labN,
    const float* __restrict__ a_src, const float* __restrict__ a_dst,
    const float* __restrict__ c01, const int* __restrict__ bucket_base,
    const int* __restrict__ blkcnt, const int* __restrict__ offc,
    uint2* __restrict__ bins, float* __restrict__ out,
    float2* __restrict__ eat2, int NV) {
  __shared__ int cur[NBK];
  __shared__ int wc[4];
  __shared__ int lbase;
  int b = blockIdx.x, tid = threadIdx.x;
  for (int i = tid; i < NBK; i += 256) cur[i] = bucket_base[i] + blkcnt[i * NCB + b];
  if (tid == 0) lbase = offc[b];
  float c0 = c01[0], c1 = c01[1];
  __syncthreads();
  int lane = tid & 63, wid = tid >> 6;
  for (int it = 0; it < ITER; ++it) {
    int e = b * CH + it * 256 + tid;
    int v = 0, s = 0, d = 0;
    float2 ea;
    if (e < NE) {
      s = src[e]; d = dst[e];
      ea = ((const float2*)eattr)[e];
      float al = a_src[s] + a_dst[d] + ea.x * c0 + ea.y * c1;
      al = (al > 0.f) ? al : 0.2f * al;
      float exv = __expf(al);
      int pos = atomicAdd(&cur[d >> 6], 1);
      uint2 pl;
      pl.x = ((unsigned)s << 6) | (unsigned)(d & 63);
      pl.y = __float_as_uint(exv);
      bins[pos] = pl;
      v = labN[s] & labN[d];
    }
    unsigned long long m = __ballot(v != 0);
    if (lane == 0) wc[wid] = __popcll(m);
    __syncthreads();
    int pre = 0;
    for (int i = 0; i < wid; i++) pre += wc[i];
    pre += __popcll(m & ((1ull << lane) - 1ull));
    if (v) {
      int p = lbase + pre;
      if (p < NV) {
        out[p] = (float)s;
        out[NV + p] = (float)d;
        eat2[p] = ea;
      }
    }
    __syncthreads();
    if (tid == 0) lbase += wc[0] + wc[1] + wc[2] + wc[3];
  }
}

// Pass 4: one block per 64-node bucket. Counting-sort the bucket's payloads by
// local node in LDS (int atomics only), then walk each node's contiguous run
// with 16 lanes/node accumulating in REGISTERS (no f32 atomics, no shuffles;
// x[s] loads are broadcast within each 16-lane group). Fused norm+bias+relu.
__global__ __launch_bounds__(512) void kagg(
    const uint2* __restrict__ bins, const int* __restrict__ bucket_base,
    const float* __restrict__ x, const float* __restrict__ Wg,
    const float* __restrict__ bg, float* __restrict__ xh) {
  __shared__ uint2 pay[CAP];
  __shared__ int cnt[64], inc[64], cur[64];
  __shared__ float sWg[80], sbg[16];
  int k = blockIdx.x, tid = threadIdx.x;
  if (tid < 80) sWg[tid] = Wg[tid];
  else if (tid < 96) sbg[tid - 80] = bg[tid - 80];
  int start = bucket_base[k], end = bucket_base[k + 1];
  int node0 = k << 6;
  int c = tid & 15, g = tid >> 4;     // g: 0..31
  __syncthreads();
  float w0 = sWg[c], w1 = sWg[16 + c], w2 = sWg[32 + c], w3 = sWg[48 + c], w4 = sWg[64 + c];
  float acc[2] = {0.f, 0.f}, den[2] = {0.f, 0.f};
  for (int cb = start; cb < end; cb += CAP) {        // single round in practice
    int n = min(end - cb, CAP);
    if (tid < 64) cnt[tid] = 0;
    __syncthreads();
    uint2 st0, st1, st2, st3, st4;                   // register-staged payloads
    {
      int i;
      i = tid;          if (i < n) { st0 = bins[cb + i]; atomicAdd(&cnt[st0.x & 63], 1); }
      i = tid + 512;    if (i < n) { st1 = bins[cb + i]; atomicAdd(&cnt[st1.x & 63], 1); }
      i = tid + 1024;   if (i < n) { st2 = bins[cb + i]; atomicAdd(&cnt[st2.x & 63], 1); }
      i = tid + 1536;   if (i < n) { st3 = bins[cb + i]; atomicAdd(&cnt[st3.x & 63], 1); }
      i = tid + 2048;   if (i < n) { st4 = bins[cb + i]; atomicAdd(&cnt[st4.x & 63], 1); }
    }
    __syncthreads();
    if (tid < 64) inc[tid] = cnt[tid];
    __syncthreads();
    for (int d = 1; d < 64; d <<= 1) {
      int v = 0;
      if (tid >= d && tid < 64) v = inc[tid - d];
      __syncthreads();
      if (tid < 64) inc[tid] += v;
      __syncthreads();
    }
    if (tid < 64) cur[tid] = inc[tid] - cnt[tid];
    __syncthreads();
    {
      int i;
      i = tid;          if (i < n) pay[atomicAdd(&cur[st0.x & 63], 1)] = st0;
      i = tid + 512;    if (i < n) pay[atomicAdd(&cur[st1.x & 63], 1)] = st1;
      i = tid + 1024;   if (i < n) pay[atomicAdd(&cur[st2.x & 63], 1)] = st2;
      i = tid + 1536;   if (i < n) pay[atomicAdd(&cur[st3.x & 63], 1)] = st3;
      i = tid + 2048;   if (i < n) pay[atomicAdd(&cur[st4.x & 63], 1)] = st4;
    }
    __syncthreads();
#pragma unroll
    for (int p = 0; p < 2; ++p) {
      int nd = p * 32 + g;
      int re = inc[nd], rs = re - cnt[nd];
      float a = 0.f, ds = 0.f;
      for (int idx = rs; idx < re; ++idx) {
        uint2 pl = pay[idx];                         // broadcast ds_read_b64
        int s = (int)(pl.x >> 6);
        float exv = __uint_as_float(pl.y);
        const float* xp = x + s * 5;                 // broadcast within group
        float h = xp[0] * w0 + xp[1] * w1 + xp[2] * w2 + xp[3] * w3 + xp[4] * w4;
        a += h * exv;
        ds += exv;
      }
      acc[p] += a; den[p] += ds;
    }
    __syncthreads();
  }
#pragma unroll
  for (int p = 0; p < 2; ++p) {
    int node = node0 + p * 32 + g;
    if (node < NN) {
      float dn = fmaxf(den[p], 1e-30f);
      float v = acc[p] / dn + sbg[c];
      xh[node * 16 + c] = (v > 0.f) ? v : 0.f;
    }
  }
}

// edge MLP, 4-edge register-blocked: each thread owns 4 edges. Every broadcast
// ds_read_b128 of a W1 row-slice now feeds 16 FMAs (was 4) -> LDS wave-insts
// per edge drop 544 -> ~148, loop overhead amortized 4x, 4 independent FMA
// chains for ILP. Summation order identical to the round-0 kernel.
__global__ __launch_bounds__(256, 2) void kmlp(
    const float2* __restrict__ eat2, const float* __restrict__ xh,
    const float* __restrict__ W1, const float* __restrict__ b1,
    const float* __restrict__ W2, const float* __restrict__ b2,
    float* __restrict__ out, int NV) {
  __shared__ __align__(16) float sW1[34 * 64];
  __shared__ __align__(16) float sb1[64];
  __shared__ __align__(16) float sW2[128];
  __shared__ float sb2[2];
  for (int i = threadIdx.x; i < 34 * 64; i += 256) sW1[i] = W1[i];
  if (threadIdx.x < 64) sb1[threadIdx.x] = b1[threadIdx.x];
  if (threadIdx.x < 128) sW2[threadIdx.x] = W2[threadIdx.x];
  if (threadIdx.x < 2) sb2[threadIdx.x] = b2[threadIdx.x];
  __syncthreads();
  int base = blockIdx.x * 1024 + threadIdx.x;
  int pe[4];
  bool ve[4];
  float f[4][34];
  float o0[4], o1[4];
#pragma unroll
  for (int e = 0; e < 4; e++) {
    int p = base + e * 256;
    pe[e] = p;
    ve[e] = (p < NV);
    int s = 0, d = 0;
    float2 ea = make_float2(0.f, 0.f);
    if (ve[e]) {
      s = (int)out[p];
      d = (int)out[NV + p];
      ea = eat2[p];
    }
    const float4* xs = (const float4*)(xh + s * 16);
    const float4* xd = (const float4*)(xh + d * 16);
#pragma unroll
    for (int q = 0; q < 4; q++) {
      float4 t = xs[q];
      f[e][q * 4 + 0] = t.x; f[e][q * 4 + 1] = t.y;
      f[e][q * 4 + 2] = t.z; f[e][q * 4 + 3] = t.w;
    }
    f[e][16] = ea.x; f[e][17] = ea.y;
#pragma unroll
    for (int q = 0; q < 4; q++) {
      float4 t = xd[q];
      f[e][18 + q * 4 + 0] = t.x; f[e][18 + q * 4 + 1] = t.y;
      f[e][18 + q * 4 + 2] = t.z; f[e][18 + q * 4 + 3] = t.w;
    }
    o0[e] = sb2[0];
    o1[e] = sb2[1];
  }
  for (int jb = 0; jb < 64; jb += 4) {
    float4 bb4 = *(const float4*)(sb1 + jb);
    float4 acc0 = bb4, acc1 = bb4, acc2 = bb4, acc3 = bb4;
#pragma unroll
    for (int i = 0; i < 34; i++) {
      float4 w = *(const float4*)(sW1 + i * 64 + jb);
      acc0.x += f[0][i] * w.x; acc0.y += f[0][i] * w.y;
      acc0.z += f[0][i] * w.z; acc0.w += f[0][i] * w.w;
      acc1.x += f[1][i] * w.x; acc1.y += f[1][i] * w.y;
      acc1.z += f[1][i] * w.z; acc1.w += f[1][i] * w.w;
      acc2.x += f[2][i] * w.x; acc2.y += f[2][i] * w.y;
      acc2.z += f[2][i] * w.z; acc2.w += f[2][i] * w.w;
      acc3.x += f[3][i] * w.x; acc3.y += f[3][i] * w.y;
      acc3.z += f[3][i] * w.z; acc3.w += f[3][i] * w.w;
    }
    // W2 slice for these 4 hidden cols: interleaved [j][2] layout
    float4 wa = *(const float4*)(sW2 + jb * 2);      // W2[jb][0],W2[jb][1],W2[jb+1][0],W2[jb+1][1]
    float4 wb = *(const float4*)(sW2 + jb * 2 + 4);  // W2[jb+2..3][0..1]
    {
      float h0 = fmaxf(acc0.x, 0.f), h1 = fmaxf(acc0.y, 0.f);
      float h2 = fmaxf(acc0.z, 0.f), h3 = fmaxf(acc0.w, 0.f);
      o0[0] += h0 * wa.x + h1 * wa.z + h2 * wb.x + h3 * wb.z;
      o1[0] += h0 * wa.y + h1 * wa.w + h2 * wb.y + h3 * wb.w;
    }
    {
      float h0 = fmaxf(acc1.x, 0.f), h1 = fmaxf(acc1.y, 0.f);
      float h2 = fmaxf(acc1.z, 0.f), h3 = fmaxf(acc1.w, 0.f);
      o0[1] += h0 * wa.x + h1 * wa.z + h2 * wb.x + h3 * wb.z;
      o1[1] += h0 * wa.y + h1 * wa.w + h2 * wb.y + h3 * wb.w;
    }
    {
      float h0 = fmaxf(acc2.x, 0.f), h1 = fmaxf(acc2.y, 0.f);
      float h2 = fmaxf(acc2.z, 0.f), h3 = fmaxf(acc2.w, 0.f);
      o0[2] += h0 * wa.x + h1 * wa.z + h2 * wb.x + h3 * wb.z;
      o1[2] += h0 * wa.y + h1 * wa.w + h2 * wb.y + h3 * wb.w;
    }
    {
      float h0 = fmaxf(acc3.x, 0.f), h1 = fmaxf(acc3.y, 0.f);
      float h2 = fmaxf(acc3.z, 0.f), h3 = fmaxf(acc3.w, 0.f);
      o0[3] += h0 * wa.x + h1 * wa.z + h2 * wb.x + h3 * wb.z;
      o1[3] += h0 * wa.y + h1 * wa.w + h2 * wb.y + h3 * wb.w;
    }
  }
#pragma unroll
  for (int e = 0; e < 4; e++) {
    if (ve[e]) {
      out[2 * NV + 2 * pe[e] + 0] = 1.f / (1.f + __expf(-o0[e]));
      out[2 * NV + 2 * pe[e] + 1] = 1.f / (1.f + __expf(-o1[e]));
    }
  }
}

static inline size_t al64(size_t v) { return (v + 63) & ~(size_t)63; }

extern "C" void kernel_launch(void* const* d_in, const int* in_sizes, int n_in,
                              void* d_out, int out_size, void* d_ws, size_t ws_size,
                              hipStream_t stream) {
  const float* x     = (const float*)d_in[0];
  const int*   edges = (const int*)d_in[1];
  const float* eattr = (const float*)d_in[2];
  const void*  labels= d_in[3];
  const float* Wg    = (const float*)d_in[4];
  const float* atts  = (const float*)d_in[5];
  const float* attd  = (const float*)d_in[6];
  const float* We    = (const float*)d_in[7];
  const float* atte  = (const float*)d_in[8];
  const float* bg    = (const float*)d_in[9];
  const float* W1    = (const float*)d_in[10];
  const float* b1    = (const float*)d_in[11];
  const float* W2    = (const float*)d_in[12];
  const float* b2    = (const float*)d_in[13];
  float* out = (float*)d_out;
  const int NV = out_size / 4;
  const int* src = edges;
  const int* dst = edges + NE;

  char* w = (char*)d_ws;
  float* xh    = (float*)w;   w += al64((size_t)NN * 64);
  uint2* bins  = (uint2*)w;   w += al64((size_t)NE * 8);
  float2* eat2 = (float2*)w;  w += al64((size_t)NV * 8);
  float* a_src = (float*)w;   w += al64((size_t)NN * 4);
  float* a_dst = (float*)w;   w += al64((size_t)NN * 4);
  int* labN    = (int*)w;     w += al64((size_t)NN * 4);
  int* blkcnt  = (int*)w;     w += al64((size_t)NBK * NCB * 4);
  int* total   = (int*)w;     w += al64((size_t)NBK * 4);
  int* bb      = (int*)w;     w += al64((size_t)(NBK + 1) * 4);
  int* cntc    = (int*)w;     w += al64((size_t)NCB * 4);
  int* offc    = (int*)w;     w += al64((size_t)(NCB + 1) * 4);
  float* c01   = (float*)w;   w += 64;
  int* flags   = (int*)w;     w += 64;

  kdetect<<<1, 256, 0, stream>>>((const unsigned char*)labels, flags);
  klab<<<(NN + 255) / 256, 256, 0, stream>>>(labels, flags, labN);
  kc01<<<1, 64, 0, stream>>>(We, atte, c01);
  knodeA<<<(NN + 255) / 256, 256, 0, stream>>>(x, Wg, atts, attd, a_src, a_dst);
  khist<<<NCB, 256, 0, stream>>>(src, dst, labN, blkcnt, cntc);
  kscanb<<<NBK, 256, 0, stream>>>(blkcnt, total);
  kscan<<<1, 256, 0, stream>>>(total, bb, NBK);
  kscan<<<1, 256, 0, stream>>>(cntc, offc, NCB);
  kscat<<<NCB, 256, 0, stream>>>(src, dst, eattr, labN, a_src, a_dst, c01, bb, blkcnt,
                                 offc, bins, out, eat2, NV);
  kagg<<<NBK, 512, 0, stream>>>(bins, bb, x, Wg, bg, xh);
  if (NV > 0)
    kmlp<<<(NV + 1023) / 1024, 256, 0, stream>>>(eat2, xh, W1, b1, W2, b2, out, NV);
}

// Round 3
// 346.390 us; speedup vs baseline: 1.1962x; 1.1353x over previous
//
#include <hip/hip_runtime.h>

#define NN 100000
#define NE 3200000
#define CH 8192                        // edges per chunk
#define NCB ((NE + CH - 1) / CH)       // 391 chunks
#define ITER (CH / 256)                // 32
#define NBK ((NN + 63) >> 6)           // 1563 dst-buckets of 64 nodes
#define CAP 2560                       // payload capacity per sort round (5*512)

// Detect label storage: int32 (harness-normalized) vs raw uint8 bool.
__global__ void kdetect(const unsigned char* __restrict__ lab8, int* __restrict__ flags) {
  __shared__ int tmp[256];
  int t = threadIdx.x;
  int s = 0;
  for (int i = t; i < 25000; i += 256) s += lab8[4 * i + 1];
  tmp[t] = s;
  __syncthreads();
  for (int d = 128; d > 0; d >>= 1) { if (t < d) tmp[t] += tmp[t + d]; __syncthreads(); }
  if (t == 0) flags[0] = (tmp[0] != 0) ? 1 : 0;
}

__global__ void klab(const void* __restrict__ lab, const int* __restrict__ flags,
                     int* __restrict__ labN) {
  int n = blockIdx.x * 256 + threadIdx.x;
  if (n >= NN) return;
  int v;
  if (flags[0]) v = ((const unsigned char*)lab)[n];
  else          v = ((const int*)lab)[n];
  labN[n] = (v != 0) ? 1 : 0;
}

// c01 = W_edge @ att_edge
__global__ void kc01(const float* __restrict__ We, const float* __restrict__ ae,
                     float* __restrict__ c01) {
  if (threadIdx.x == 0) {
    float c0 = 0.f, c1 = 0.f;
    for (int k = 0; k < 16; k++) { c0 += We[k] * ae[k]; c1 += We[16 + k] * ae[k]; }
    c01[0] = c0; c01[1] = c1;
  }
}

// a_src = (x@Wg)@att_src ; a_dst = (x@Wg)@att_dst  (h not materialized)
__global__ void knodeA(const float* __restrict__ x, const float* __restrict__ Wg,
                       const float* __restrict__ atts, const float* __restrict__ attd,
                       float* __restrict__ a_src, float* __restrict__ a_dst) {
  int n = blockIdx.x * 256 + threadIdx.x;
  if (n >= NN) return;
  float xi[5];
#pragma unroll
  for (int i = 0; i < 5; i++) xi[i] = x[n * 5 + i];
  float asum = 0.f, dsum = 0.f;
#pragma unroll
  for (int k = 0; k < 16; k++) {
    float acc = 0.f;
#pragma unroll
    for (int i = 0; i < 5; i++) acc += xi[i] * Wg[i * 16 + k];
    asum += acc * atts[k];
    dsum += acc * attd[k];
  }
  a_src[n] = asum; a_dst[n] = dsum;
}

// Pass 1: per-chunk bucket histogram + per-chunk valid-edge count.
__global__ __launch_bounds__(256) void khist(const int* __restrict__ src,
                                             const int* __restrict__ dst,
                                             const int* __restrict__ labN,
                                             int* __restrict__ blkcnt,
                                             int* __restrict__ cntc) {
  __shared__ int hist[NBK];
  __shared__ int vsum;
  int tid = threadIdx.x, b = blockIdx.x;
  for (int i = tid; i < NBK; i += 256) hist[i] = 0;
  if (tid == 0) vsum = 0;
  __syncthreads();
  int wsum = 0;
  for (int it = 0; it < ITER; ++it) {
    int e = b * CH + it * 256 + tid;
    int v = 0;
    if (e < NE) {
      int s = src[e], d = dst[e];
      atomicAdd(&hist[d >> 6], 1);
      v = labN[s] & labN[d];
    }
    unsigned long long m = __ballot(v != 0);
    wsum += __popcll(m);
  }
  if ((tid & 63) == 0) atomicAdd(&vsum, wsum);
  __syncthreads();
  for (int i = tid; i < NBK; i += 256) blkcnt[i * NCB + b] = hist[i];
  if (tid == 0) cntc[b] = vsum;
}

// Pass 2a: per-bucket exclusive scan over chunks (row of blkcnt), totals out.
__global__ __launch_bounds__(256) void kscanb(int* __restrict__ blkcnt,
                                              int* __restrict__ total) {
  __shared__ int a[512];
  int row = blockIdx.x, t = threadIdx.x;
  int* p = blkcnt + row * NCB;
  int o0 = (t < NCB) ? p[t] : 0;
  int o1 = (t + 256 < NCB) ? p[t + 256] : 0;
  a[t] = o0; a[t + 256] = o1;
  __syncthreads();
  for (int d = 1; d < 512; d <<= 1) {
    int x0 = (t >= d) ? a[t - d] : 0;
    int x1 = (t + 256 >= d) ? a[t + 256 - d] : 0;
    __syncthreads();
    a[t] += x0; a[t + 256] += x1;
    __syncthreads();
  }
  if (t < NCB) p[t] = a[t] - o0;
  if (t + 256 < NCB) p[t + 256] = a[t + 256] - o1;
  if (t == 0) total[row] = a[NCB - 1];
}

// generic single-block exclusive scan; also writes off[nb] = grand total
__global__ void kscan(const int* __restrict__ cnt, int* __restrict__ off, int nb) {
  __shared__ int tmp[256];
  __shared__ int carry;
  int t = threadIdx.x;
  if (t == 0) carry = 0;
  __syncthreads();
  for (int base = 0; base < nb; base += 256) {
    int i = base + t;
    int v = (i < nb) ? cnt[i] : 0;
    tmp[t] = v;
    __syncthreads();
    for (int d = 1; d < 256; d <<= 1) {
      int add = (t >= d) ? tmp[t - d] : 0;
      __syncthreads();
      tmp[t] += add;
      __syncthreads();
    }
    if (i < nb) off[i] = carry + tmp[t] - v;
    __syncthreads();
    if (t == 0) carry += tmp[255];
    __syncthreads();
  }
  if (t == 0) off[nb] = carry;
}

// Pass 3: compute ex, scatter (src,ldst,ex) to bins via LDS cursors; ALSO the
// ordered output compaction (out src/dst + compacted edge_attr) fused in.
__global__ __launch_bounds__(256) void kscat(
    const int* __restrict__ src, const int* __restrict__ dst,
    const float* __restrict__ eattr, const int* __restrict__ labN,
    const float* __restrict__ a_src, const float* __restrict__ a_dst,
    const float* __restrict__ c01, const int* __restrict__ bucket_base,
    const int* __restrict__ blkcnt, const int* __restrict__ offc,
    uint2* __restrict__ bins, float* __restrict__ out,
    float2* __restrict__ eat2, int NV) {
  __shared__ int cur[NBK];
  __shared__ int wc[4];
  __shared__ int lbase;
  int b = blockIdx.x, tid = threadIdx.x;
  for (int i = tid; i < NBK; i += 256) cur[i] = bucket_base[i] + blkcnt[i * NCB + b];
  if (tid == 0) lbase = offc[b];
  float c0 = c01[0], c1 = c01[1];
  __syncthreads();
  int lane = tid & 63, wid = tid >> 6;
  for (int it = 0; it < ITER; ++it) {
    int e = b * CH + it * 256 + tid;
    int v = 0, s = 0, d = 0;
    float2 ea;
    if (e < NE) {
      s = src[e]; d = dst[e];
      ea = ((const float2*)eattr)[e];
      float al = a_src[s] + a_dst[d] + ea.x * c0 + ea.y * c1;
      al = (al > 0.f) ? al : 0.2f * al;
      float exv = __expf(al);
      int pos = atomicAdd(&cur[d >> 6], 1);
      uint2 pl;
      pl.x = ((unsigned)s << 6) | (unsigned)(d & 63);
      pl.y = __float_as_uint(exv);
      bins[pos] = pl;
      v = labN[s] & labN[d];
    }
    unsigned long long m = __ballot(v != 0);
    if (lane == 0) wc[wid] = __popcll(m);
    __syncthreads();
    int pre = 0;
    for (int i = 0; i < wid; i++) pre += wc[i];
    pre += __popcll(m & ((1ull << lane) - 1ull));
    if (v) {
      int p = lbase + pre;
      if (p < NV) {
        out[p] = (float)s;
        out[NV + p] = (float)d;
        eat2[p] = ea;
      }
    }
    __syncthreads();
    if (tid == 0) lbase += wc[0] + wc[1] + wc[2] + wc[3];
  }
}

// Pass 4: one block per 64-node bucket. Counting-sort the bucket's payloads by
// local node in LDS (int atomics only), then walk each node's contiguous run
// with 16 lanes/node accumulating in REGISTERS (no f32 atomics, no shuffles;
// x[s] loads are broadcast within each 16-lane group). Fused norm+bias+relu.
__global__ __launch_bounds__(512) void kagg(
    const uint2* __restrict__ bins, const int* __restrict__ bucket_base,
    const float* __restrict__ x, const float* __restrict__ Wg,
    const float* __restrict__ bg, float* __restrict__ xh) {
  __shared__ uint2 pay[CAP];
  __shared__ int cnt[64], inc[64], cur[64];
  __shared__ float sWg[80], sbg[16];
  int k = blockIdx.x, tid = threadIdx.x;
  if (tid < 80) sWg[tid] = Wg[tid];
  else if (tid < 96) sbg[tid - 80] = bg[tid - 80];
  int start = bucket_base[k], end = bucket_base[k + 1];
  int node0 = k << 6;
  int c = tid & 15, g = tid >> 4;     // g: 0..31
  __syncthreads();
  float w0 = sWg[c], w1 = sWg[16 + c], w2 = sWg[32 + c], w3 = sWg[48 + c], w4 = sWg[64 + c];
  float acc[2] = {0.f, 0.f}, den[2] = {0.f, 0.f};
  for (int cb = start; cb < end; cb += CAP) {        // single round in practice
    int n = min(end - cb, CAP);
    if (tid < 64) cnt[tid] = 0;
    __syncthreads();
    uint2 st0, st1, st2, st3, st4;                   // register-staged payloads
    {
      int i;
      i = tid;          if (i < n) { st0 = bins[cb + i]; atomicAdd(&cnt[st0.x & 63], 1); }
      i = tid + 512;    if (i < n) { st1 = bins[cb + i]; atomicAdd(&cnt[st1.x & 63], 1); }
      i = tid + 1024;   if (i < n) { st2 = bins[cb + i]; atomicAdd(&cnt[st2.x & 63], 1); }
      i = tid + 1536;   if (i < n) { st3 = bins[cb + i]; atomicAdd(&cnt[st3.x & 63], 1); }
      i = tid + 2048;   if (i < n) { st4 = bins[cb + i]; atomicAdd(&cnt[st4.x & 63], 1); }
    }
    __syncthreads();
    if (tid < 64) inc[tid] = cnt[tid];
    __syncthreads();
    for (int d = 1; d < 64; d <<= 1) {
      int v = 0;
      if (tid >= d && tid < 64) v = inc[tid - d];
      __syncthreads();
      if (tid < 64) inc[tid] += v;
      __syncthreads();
    }
    if (tid < 64) cur[tid] = inc[tid] - cnt[tid];
    __syncthreads();
    {
      int i;
      i = tid;          if (i < n) pay[atomicAdd(&cur[st0.x & 63], 1)] = st0;
      i = tid + 512;    if (i < n) pay[atomicAdd(&cur[st1.x & 63], 1)] = st1;
      i = tid + 1024;   if (i < n) pay[atomicAdd(&cur[st2.x & 63], 1)] = st2;
      i = tid + 1536;   if (i < n) pay[atomicAdd(&cur[st3.x & 63], 1)] = st3;
      i = tid + 2048;   if (i < n) pay[atomicAdd(&cur[st4.x & 63], 1)] = st4;
    }
    __syncthreads();
#pragma unroll
    for (int p = 0; p < 2; ++p) {
      int nd = p * 32 + g;
      int re = inc[nd], rs = re - cnt[nd];
      float a = 0.f, ds = 0.f;
      for (int idx = rs; idx < re; ++idx) {
        uint2 pl = pay[idx];                         // broadcast ds_read_b64
        int s = (int)(pl.x >> 6);
        float exv = __uint_as_float(pl.y);
        const float* xp = x + s * 5;                 // broadcast within group
        float h = xp[0] * w0 + xp[1] * w1 + xp[2] * w2 + xp[3] * w3 + xp[4] * w4;
        a += h * exv;
        ds += exv;
      }
      acc[p] += a; den[p] += ds;
    }
    __syncthreads();
  }
#pragma unroll
  for (int p = 0; p < 2; ++p) {
    int node = node0 + p * 32 + g;
    if (node < NN) {
      float dn = fmaxf(den[p], 1e-30f);
      float v = acc[p] / dn + sbg[c];
      xh[node * 16 + c] = (v > 0.f) ? v : 0.f;
    }
  }
}

// edge MLP, 2-edge register-blocked: f0[34]+f1[34] = 68 VGPRs (fits — round-2's
// 4-edge version needed ~170 and spilled, VGPR_Count=92 proved it). Each
// broadcast ds_read_b128 of a W1 row-slice feeds 8 FMAs (was 4); LDS instrs
// per edge 544 -> 272; two independent FMA chains for ILP. Summation order
// identical to round-0.
__global__ __launch_bounds__(256, 4) void kmlp(
    const float2* __restrict__ eat2, const float* __restrict__ xh,
    const float* __restrict__ W1, const float* __restrict__ b1,
    const float* __restrict__ W2, const float* __restrict__ b2,
    float* __restrict__ out, int NV) {
  __shared__ __align__(16) float sW1[34 * 64];
  __shared__ __align__(16) float sb1[64];
  __shared__ __align__(16) float sW2[128];
  __shared__ float sb2[2];
  for (int i = threadIdx.x; i < 34 * 64; i += 256) sW1[i] = W1[i];
  if (threadIdx.x < 64) sb1[threadIdx.x] = b1[threadIdx.x];
  if (threadIdx.x < 128) sW2[threadIdx.x] = W2[threadIdx.x];
  if (threadIdx.x < 2) sb2[threadIdx.x] = b2[threadIdx.x];
  __syncthreads();
  int p0 = blockIdx.x * 512 + threadIdx.x;
  int p1 = p0 + 256;
  bool v0 = (p0 < NV), v1 = (p1 < NV);
  float f0[34], f1[34];
  {
    int s = 0, d = 0;
    float2 ea = make_float2(0.f, 0.f);
    if (v0) { s = (int)out[p0]; d = (int)out[NV + p0]; ea = eat2[p0]; }
    const float4* xs = (const float4*)(xh + s * 16);
    const float4* xd = (const float4*)(xh + d * 16);
#pragma unroll
    for (int q = 0; q < 4; q++) {
      float4 t = xs[q];
      f0[q * 4 + 0] = t.x; f0[q * 4 + 1] = t.y; f0[q * 4 + 2] = t.z; f0[q * 4 + 3] = t.w;
    }
    f0[16] = ea.x; f0[17] = ea.y;
#pragma unroll
    for (int q = 0; q < 4; q++) {
      float4 t = xd[q];
      f0[18 + q * 4 + 0] = t.x; f0[18 + q * 4 + 1] = t.y;
      f0[18 + q * 4 + 2] = t.z; f0[18 + q * 4 + 3] = t.w;
    }
  }
  {
    int s = 0, d = 0;
    float2 ea = make_float2(0.f, 0.f);
    if (v1) { s = (int)out[p1]; d = (int)out[NV + p1]; ea = eat2[p1]; }
    const float4* xs = (const float4*)(xh + s * 16);
    const float4* xd = (const float4*)(xh + d * 16);
#pragma unroll
    for (int q = 0; q < 4; q++) {
      float4 t = xs[q];
      f1[q * 4 + 0] = t.x; f1[q * 4 + 1] = t.y; f1[q * 4 + 2] = t.z; f1[q * 4 + 3] = t.w;
    }
    f1[16] = ea.x; f1[17] = ea.y;
#pragma unroll
    for (int q = 0; q < 4; q++) {
      float4 t = xd[q];
      f1[18 + q * 4 + 0] = t.x; f1[18 + q * 4 + 1] = t.y;
      f1[18 + q * 4 + 2] = t.z; f1[18 + q * 4 + 3] = t.w;
    }
  }
  float oa0 = sb2[0], oa1 = sb2[1];   // edge 0 outputs
  float ob0 = sb2[0], ob1 = sb2[1];   // edge 1 outputs
  for (int jb = 0; jb < 64; jb += 4) {
    float4 bb4 = *(const float4*)(sb1 + jb);
    float4 accA = bb4, accB = bb4;
#pragma unroll
    for (int i = 0; i < 34; i++) {
      float4 w = *(const float4*)(sW1 + i * 64 + jb);
      float fa = f0[i], fb = f1[i];
      accA.x += fa * w.x; accA.y += fa * w.y; accA.z += fa * w.z; accA.w += fa * w.w;
      accB.x += fb * w.x; accB.y += fb * w.y; accB.z += fb * w.z; accB.w += fb * w.w;
    }
    float4 wa = *(const float4*)(sW2 + jb * 2);      // W2[jb..jb+1][0..1]
    float4 wb = *(const float4*)(sW2 + jb * 2 + 4);  // W2[jb+2..jb+3][0..1]
    {
      float h0 = fmaxf(accA.x, 0.f), h1 = fmaxf(accA.y, 0.f);
      float h2 = fmaxf(accA.z, 0.f), h3 = fmaxf(accA.w, 0.f);
      oa0 += h0 * wa.x + h1 * wa.z + h2 * wb.x + h3 * wb.z;
      oa1 += h0 * wa.y + h1 * wa.w + h2 * wb.y + h3 * wb.w;
    }
    {
      float h0 = fmaxf(accB.x, 0.f), h1 = fmaxf(accB.y, 0.f);
      float h2 = fmaxf(accB.z, 0.f), h3 = fmaxf(accB.w, 0.f);
      ob0 += h0 * wa.x + h1 * wa.z + h2 * wb.x + h3 * wb.z;
      ob1 += h0 * wa.y + h1 * wa.w + h2 * wb.y + h3 * wb.w;
    }
  }
  if (v0) {
    out[2 * NV + 2 * p0 + 0] = 1.f / (1.f + __expf(-oa0));
    out[2 * NV + 2 * p0 + 1] = 1.f / (1.f + __expf(-oa1));
  }
  if (v1) {
    out[2 * NV + 2 * p1 + 0] = 1.f / (1.f + __expf(-ob0));
    out[2 * NV + 2 * p1 + 1] = 1.f / (1.f + __expf(-ob1));
  }
}

static inline size_t al64(size_t v) { return (v + 63) & ~(size_t)63; }

extern "C" void kernel_launch(void* const* d_in, const int* in_sizes, int n_in,
                              void* d_out, int out_size, void* d_ws, size_t ws_size,
                              hipStream_t stream) {
  const float* x     = (const float*)d_in[0];
  const int*   edges = (const int*)d_in[1];
  const float* eattr = (const float*)d_in[2];
  const void*  labels= d_in[3];
  const float* Wg    = (const float*)d_in[4];
  const float* atts  = (const float*)d_in[5];
  const float* attd  = (const float*)d_in[6];
  const float* We    = (const float*)d_in[7];
  const float* atte  = (const float*)d_in[8];
  const float* bg    = (const float*)d_in[9];
  const float* W1    = (const float*)d_in[10];
  const float* b1    = (const float*)d_in[11];
  const float* W2    = (const float*)d_in[12];
  const float* b2    = (const float*)d_in[13];
  float* out = (float*)d_out;
  const int NV = out_size / 4;
  const int* src = edges;
  const int* dst = edges + NE;

  char* w = (char*)d_ws;
  float* xh    = (float*)w;   w += al64((size_t)NN * 64);
  uint2* bins  = (uint2*)w;   w += al64((size_t)NE * 8);
  float2* eat2 = (float2*)w;  w += al64((size_t)NV * 8);
  float* a_src = (float*)w;   w += al64((size_t)NN * 4);
  float* a_dst = (float*)w;   w += al64((size_t)NN * 4);
  int* labN    = (int*)w;     w += al64((size_t)NN * 4);
  int* blkcnt  = (int*)w;     w += al64((size_t)NBK * NCB * 4);
  int* total   = (int*)w;     w += al64((size_t)NBK * 4);
  int* bb      = (int*)w;     w += al64((size_t)(NBK + 1) * 4);
  int* cntc    = (int*)w;     w += al64((size_t)NCB * 4);
  int* offc    = (int*)w;     w += al64((size_t)(NCB + 1) * 4);
  float* c01   = (float*)w;   w += 64;
  int* flags   = (int*)w;     w += 64;

  kdetect<<<1, 256, 0, stream>>>((const unsigned char*)labels, flags);
  klab<<<(NN + 255) / 256, 256, 0, stream>>>(labels, flags, labN);
  kc01<<<1, 64, 0, stream>>>(We, atte, c01);
  knodeA<<<(NN + 255) / 256, 256, 0, stream>>>(x, Wg, atts, attd, a_src, a_dst);
  khist<<<NCB, 256, 0, stream>>>(src, dst, labN, blkcnt, cntc);
  kscanb<<<NBK, 256, 0, stream>>>(blkcnt, total);
  kscan<<<1, 256, 0, stream>>>(total, bb, NBK);
  kscan<<<1, 256, 0, stream>>>(cntc, offc, NCB);
  kscat<<<NCB, 256, 0, stream>>>(src, dst, eattr, labN, a_src, a_dst, c01, bb, blkcnt,
                                 offc, bins, out, eat2, NV);
  kagg<<<NBK, 512, 0, stream>>>(bins, bb, x, Wg, bg, xh);
  if (NV > 0)
    kmlp<<<(NV + 511) / 512, 256, 0, stream>>>(eat2, xh, W1, b1, W2, b2, out, NV);
}

// Round 4
// 286.269 us; speedup vs baseline: 1.4475x; 1.2100x over previous
//
#include <hip/hip_runtime.h>

#define NN 100000
#define NE 3200000
#define CH 8192                        // edges per chunk
#define NCB ((NE + CH - 1) / CH)       // 391 chunks
#define ITER (CH / 256)                // 32
#define NBK ((NN + 63) >> 6)           // 1563 dst-buckets of 64 nodes
#define CAP 2560                       // payload capacity per sort round (5*512)

typedef __attribute__((ext_vector_type(8))) __bf16 bf16x8;
typedef __attribute__((ext_vector_type(4))) float f32x4;

union BF8 { unsigned short u[8]; bf16x8 v; };

// Detect label storage: int32 (harness-normalized) vs raw uint8 bool.
__global__ void kdetect(const unsigned char* __restrict__ lab8, int* __restrict__ flags) {
  __shared__ int tmp[256];
  int t = threadIdx.x;
  int s = 0;
  for (int i = t; i < 25000; i += 256) s += lab8[4 * i + 1];
  tmp[t] = s;
  __syncthreads();
  for (int d = 128; d > 0; d >>= 1) { if (t < d) tmp[t] += tmp[t + d]; __syncthreads(); }
  if (t == 0) flags[0] = (tmp[0] != 0) ? 1 : 0;
}

__global__ void klab(const void* __restrict__ lab, const int* __restrict__ flags,
                     int* __restrict__ labN) {
  int n = blockIdx.x * 256 + threadIdx.x;
  if (n >= NN) return;
  int v;
  if (flags[0]) v = ((const unsigned char*)lab)[n];
  else          v = ((const int*)lab)[n];
  labN[n] = (v != 0) ? 1 : 0;
}

// c01 = W_edge @ att_edge
__global__ void kc01(const float* __restrict__ We, const float* __restrict__ ae,
                     float* __restrict__ c01) {
  if (threadIdx.x == 0) {
    float c0 = 0.f, c1 = 0.f;
    for (int k = 0; k < 16; k++) { c0 += We[k] * ae[k]; c1 += We[16 + k] * ae[k]; }
    c01[0] = c0; c01[1] = c1;
  }
}

// a_src = (x@Wg)@att_src ; a_dst = (x@Wg)@att_dst  (h not materialized)
__global__ void knodeA(const float* __restrict__ x, const float* __restrict__ Wg,
                       const float* __restrict__ atts, const float* __restrict__ attd,
                       float* __restrict__ a_src, float* __restrict__ a_dst) {
  int n = blockIdx.x * 256 + threadIdx.x;
  if (n >= NN) return;
  float xi[5];
#pragma unroll
  for (int i = 0; i < 5; i++) xi[i] = x[n * 5 + i];
  float asum = 0.f, dsum = 0.f;
#pragma unroll
  for (int k = 0; k < 16; k++) {
    float acc = 0.f;
#pragma unroll
    for (int i = 0; i < 5; i++) acc += xi[i] * Wg[i * 16 + k];
    asum += acc * atts[k];
    dsum += acc * attd[k];
  }
  a_src[n] = asum; a_dst[n] = dsum;
}

// Pass 1: per-chunk bucket histogram + per-chunk valid-edge count.
__global__ __launch_bounds__(256) void khist(const int* __restrict__ src,
                                             const int* __restrict__ dst,
                                             const int* __restrict__ labN,
                                             int* __restrict__ blkcnt,
                                             int* __restrict__ cntc) {
  __shared__ int hist[NBK];
  __shared__ int vsum;
  int tid = threadIdx.x, b = blockIdx.x;
  for (int i = tid; i < NBK; i += 256) hist[i] = 0;
  if (tid == 0) vsum = 0;
  __syncthreads();
  int wsum = 0;
  for (int it = 0; it < ITER; ++it) {
    int e = b * CH + it * 256 + tid;
    int v = 0;
    if (e < NE) {
      int s = src[e], d = dst[e];
      atomicAdd(&hist[d >> 6], 1);
      v = labN[s] & labN[d];
    }
    unsigned long long m = __ballot(v != 0);
    wsum += __popcll(m);
  }
  if ((tid & 63) == 0) atomicAdd(&vsum, wsum);
  __syncthreads();
  for (int i = tid; i < NBK; i += 256) blkcnt[i * NCB + b] = hist[i];
  if (tid == 0) cntc[b] = vsum;
}

// Pass 2a: per-bucket exclusive scan over chunks (row of blkcnt), totals out.
__global__ __launch_bounds__(256) void kscanb(int* __restrict__ blkcnt,
                                              int* __restrict__ total) {
  __shared__ int a[512];
  int row = blockIdx.x, t = threadIdx.x;
  int* p = blkcnt + row * NCB;
  int o0 = (t < NCB) ? p[t] : 0;
  int o1 = (t + 256 < NCB) ? p[t + 256] : 0;
  a[t] = o0; a[t + 256] = o1;
  __syncthreads();
  for (int d = 1; d < 512; d <<= 1) {
    int x0 = (t >= d) ? a[t - d] : 0;
    int x1 = (t + 256 >= d) ? a[t + 256 - d] : 0;
    __syncthreads();
    a[t] += x0; a[t + 256] += x1;
    __syncthreads();
  }
  if (t < NCB) p[t] = a[t] - o0;
  if (t + 256 < NCB) p[t + 256] = a[t + 256] - o1;
  if (t == 0) total[row] = a[NCB - 1];
}

// generic single-block exclusive scan; also writes off[nb] = grand total
__global__ void kscan(const int* __restrict__ cnt, int* __restrict__ off, int nb) {
  __shared__ int tmp[256];
  __shared__ int carry;
  int t = threadIdx.x;
  if (t == 0) carry = 0;
  __syncthreads();
  for (int base = 0; base < nb; base += 256) {
    int i = base + t;
    int v = (i < nb) ? cnt[i] : 0;
    tmp[t] = v;
    __syncthreads();
    for (int d = 1; d < 256; d <<= 1) {
      int add = (t >= d) ? tmp[t - d] : 0;
      __syncthreads();
      tmp[t] += add;
      __syncthreads();
    }
    if (i < nb) off[i] = carry + tmp[t] - v;
    __syncthreads();
    if (t == 0) carry += tmp[255];
    __syncthreads();
  }
  if (t == 0) off[nb] = carry;
}

// Pass 3: compute ex, scatter (src,ldst,ex) to bins via LDS cursors; ALSO the
// ordered output compaction (out src/dst + compacted edge_attr) fused in.
__global__ __launch_bounds__(256) void kscat(
    const int* __restrict__ src, const int* __restrict__ dst,
    const float* __restrict__ eattr, const int* __restrict__ labN,
    const float* __restrict__ a_src, const float* __restrict__ a_dst,
    const float* __restrict__ c01, const int* __restrict__ bucket_base,
    const int* __restrict__ blkcnt, const int* __restrict__ offc,
    uint2* __restrict__ bins, float* __restrict__ out,
    float2* __restrict__ eat2, int NV) {
  __shared__ int cur[NBK];
  __shared__ int wc[4];
  __shared__ int lbase;
  int b = blockIdx.x, tid = threadIdx.x;
  for (int i = tid; i < NBK; i += 256) cur[i] = bucket_base[i] + blkcnt[i * NCB + b];
  if (tid == 0) lbase = offc[b];
  float c0 = c01[0], c1 = c01[1];
  __syncthreads();
  int lane = tid & 63, wid = tid >> 6;
  for (int it = 0; it < ITER; ++it) {
    int e = b * CH + it * 256 + tid;
    int v = 0, s = 0, d = 0;
    float2 ea;
    if (e < NE) {
      s = src[e]; d = dst[e];
      ea = ((const float2*)eattr)[e];
      float al = a_src[s] + a_dst[d] + ea.x * c0 + ea.y * c1;
      al = (al > 0.f) ? al : 0.2f * al;
      float exv = __expf(al);
      int pos = atomicAdd(&cur[d >> 6], 1);
      uint2 pl;
      pl.x = ((unsigned)s << 6) | (unsigned)(d & 63);
      pl.y = __float_as_uint(exv);
      bins[pos] = pl;
      v = labN[s] & labN[d];
    }
    unsigned long long m = __ballot(v != 0);
    if (lane == 0) wc[wid] = __popcll(m);
    __syncthreads();
    int pre = 0;
    for (int i = 0; i < wid; i++) pre += wc[i];
    pre += __popcll(m & ((1ull << lane) - 1ull));
    if (v) {
      int p = lbase + pre;
      if (p < NV) {
        out[p] = (float)s;
        out[NV + p] = (float)d;
        eat2[p] = ea;
      }
    }
    __syncthreads();
    if (tid == 0) lbase += wc[0] + wc[1] + wc[2] + wc[3];
  }
}

// Pass 4: one block per 64-node bucket. Counting-sort the bucket's payloads by
// local node in LDS (int atomics only), then walk each node's contiguous run
// with 16 lanes/node accumulating in REGISTERS (no f32 atomics, no shuffles;
// x[s] loads are broadcast within each 16-lane group). Fused norm+bias+relu.
__global__ __launch_bounds__(512) void kagg(
    const uint2* __restrict__ bins, const int* __restrict__ bucket_base,
    const float* __restrict__ x, const float* __restrict__ Wg,
    const float* __restrict__ bg, float* __restrict__ xh) {
  __shared__ uint2 pay[CAP];
  __shared__ int cnt[64], inc[64], cur[64];
  __shared__ float sWg[80], sbg[16];
  int k = blockIdx.x, tid = threadIdx.x;
  if (tid < 80) sWg[tid] = Wg[tid];
  else if (tid < 96) sbg[tid - 80] = bg[tid - 80];
  int start = bucket_base[k], end = bucket_base[k + 1];
  int node0 = k << 6;
  int c = tid & 15, g = tid >> 4;     // g: 0..31
  __syncthreads();
  float w0 = sWg[c], w1 = sWg[16 + c], w2 = sWg[32 + c], w3 = sWg[48 + c], w4 = sWg[64 + c];
  float acc[2] = {0.f, 0.f}, den[2] = {0.f, 0.f};
  for (int cb = start; cb < end; cb += CAP) {        // single round in practice
    int n = min(end - cb, CAP);
    if (tid < 64) cnt[tid] = 0;
    __syncthreads();
    uint2 st0, st1, st2, st3, st4;                   // register-staged payloads
    {
      int i;
      i = tid;          if (i < n) { st0 = bins[cb + i]; atomicAdd(&cnt[st0.x & 63], 1); }
      i = tid + 512;    if (i < n) { st1 = bins[cb + i]; atomicAdd(&cnt[st1.x & 63], 1); }
      i = tid + 1024;   if (i < n) { st2 = bins[cb + i]; atomicAdd(&cnt[st2.x & 63], 1); }
      i = tid + 1536;   if (i < n) { st3 = bins[cb + i]; atomicAdd(&cnt[st3.x & 63], 1); }
      i = tid + 2048;   if (i < n) { st4 = bins[cb + i]; atomicAdd(&cnt[st4.x & 63], 1); }
    }
    __syncthreads();
    if (tid < 64) inc[tid] = cnt[tid];
    __syncthreads();
    for (int d = 1; d < 64; d <<= 1) {
      int v = 0;
      if (tid >= d && tid < 64) v = inc[tid - d];
      __syncthreads();
      if (tid < 64) inc[tid] += v;
      __syncthreads();
    }
    if (tid < 64) cur[tid] = inc[tid] - cnt[tid];
    __syncthreads();
    {
      int i;
      i = tid;          if (i < n) pay[atomicAdd(&cur[st0.x & 63], 1)] = st0;
      i = tid + 512;    if (i < n) pay[atomicAdd(&cur[st1.x & 63], 1)] = st1;
      i = tid + 1024;   if (i < n) pay[atomicAdd(&cur[st2.x & 63], 1)] = st2;
      i = tid + 1536;   if (i < n) pay[atomicAdd(&cur[st3.x & 63], 1)] = st3;
      i = tid + 2048;   if (i < n) pay[atomicAdd(&cur[st4.x & 63], 1)] = st4;
    }
    __syncthreads();
#pragma unroll
    for (int p = 0; p < 2; ++p) {
      int nd = p * 32 + g;
      int re = inc[nd], rs = re - cnt[nd];
      float a = 0.f, ds = 0.f;
      for (int idx = rs; idx < re; ++idx) {
        uint2 pl = pay[idx];                         // broadcast ds_read_b64
        int s = (int)(pl.x >> 6);
        float exv = __uint_as_float(pl.y);
        const float* xp = x + s * 5;                 // broadcast within group
        float h = xp[0] * w0 + xp[1] * w1 + xp[2] * w2 + xp[3] * w3 + xp[4] * w4;
        a += h * exv;
        ds += exv;
      }
      acc[p] += a; den[p] += ds;
    }
    __syncthreads();
  }
#pragma unroll
  for (int p = 0; p < 2; ++p) {
    int node = node0 + p * 32 + g;
    if (node < NN) {
      float dn = fmaxf(den[p], 1e-30f);
      float v = acc[p] / dn + sbg[c];
      xh[node * 16 + c] = (v > 0.f) ? v : 0.f;
    }
  }
}

// edge MLP via MFMA. Hidden GEMM [NV,32]x[32,64] (K=32: xh[s] ++ xh[d]; the two
// edge-attr rows of W1 are folded into the fp32 epilogue, so K fits ONE
// mfma_f32_16x16x32_bf16). fp32 accuracy recovered with a trunc hi/lo bf16
// split: D = AhBh + AhBl + AlBh (3 MFMAs, err ~2^-16). Per wave-tile of 16
// edges: 12 MFMA total. A-fragment (row=lane&15, k=(lane>>4)*8+i) is exactly 8
// consecutive floats of xh[s] or xh[d] -> direct global gather, no LDS, no
// per-thread f[34] array (the thing the compiler refused to keep in VGPRs for
// 3 rounds). B-fragments (W1) live in 32 VGPRs for the whole kernel.
__global__ __launch_bounds__(256) void kmlp(
    const float2* __restrict__ eat2, const float* __restrict__ xh,
    const float* __restrict__ W1, const float* __restrict__ b1,
    const float* __restrict__ W2, const float* __restrict__ b2,
    float* __restrict__ out, int NV) {
  int tid = threadIdx.x;
  int lane = tid & 63, wid = tid >> 6;
  int lo4 = lane & 15, q = lane >> 4;

  // ---- B fragments: W1 logical rows 0..15 (src) and 18..33 (dst), hi/lo ----
  BF8 bh[4], bl[4];
#pragma unroll
  for (int ct = 0; ct < 4; ct++) {
    int col = ct * 16 + lo4;
#pragma unroll
    for (int i = 0; i < 8; i++) {
      int k = q * 8 + i;                      // logical K index 0..31
      int r = (k < 16) ? k : (k + 2);         // skip W1 rows 16,17 (edge attr)
      float w = W1[r * 64 + col];
      unsigned u = __float_as_uint(w);
      float rem = w - __uint_as_float(u & 0xffff0000u);
      bh[ct].u[i] = (unsigned short)(u >> 16);
      bl[ct].u[i] = (unsigned short)(__float_as_uint(rem) >> 16);
    }
  }
  // ---- epilogue constants for my 4 output cols (j = ct*16+lo4) ----
  float b1v[4], w16v[4], w17v[4], w2a[4], w2b[4];
#pragma unroll
  for (int ct = 0; ct < 4; ct++) {
    int j = ct * 16 + lo4;
    b1v[ct] = b1[j];
    w16v[ct] = W1[16 * 64 + j];
    w17v[ct] = W1[17 * 64 + j];
    w2a[ct] = W2[j * 2 + 0];
    w2b[ct] = W2[j * 2 + 1];
  }
  float bias20 = b2[0], bias21 = b2[1];

  int nwaves = gridDim.x * 4;
  int ntiles = (NV + 15) >> 4;
  for (int tb = blockIdx.x * 4 + wid; tb < ntiles; tb += nwaves) {
    int base = tb * 16;
    // ---- A fragment: row = lo4 (edge base+lo4), k-slice = q*8..q*8+7 ----
    BF8 ah, al;
    {
      int p = base + lo4;
      float vals[8] = {0.f, 0.f, 0.f, 0.f, 0.f, 0.f, 0.f, 0.f};
      if (p < NV) {
        int node = (int)out[((q < 2) ? 0 : NV) + p];
        const float4* xp = (const float4*)(xh + node * 16 + (q & 1) * 8);
        float4 f0 = xp[0], f1 = xp[1];
        vals[0] = f0.x; vals[1] = f0.y; vals[2] = f0.z; vals[3] = f0.w;
        vals[4] = f1.x; vals[5] = f1.y; vals[6] = f1.z; vals[7] = f1.w;
      }
#pragma unroll
      for (int i = 0; i < 8; i++) {
        unsigned u = __float_as_uint(vals[i]);
        float rem = vals[i] - __uint_as_float(u & 0xffff0000u);
        ah.u[i] = (unsigned short)(u >> 16);
        al.u[i] = (unsigned short)(__float_as_uint(rem) >> 16);
      }
    }
    // ---- 12 MFMAs: 4 col-tiles x 3 split terms ----
    f32x4 acc[4];
#pragma unroll
    for (int ct = 0; ct < 4; ct++) {
      f32x4 z = {0.f, 0.f, 0.f, 0.f};
      z = __builtin_amdgcn_mfma_f32_16x16x32_bf16(ah.v, bh[ct].v, z, 0, 0, 0);
      z = __builtin_amdgcn_mfma_f32_16x16x32_bf16(ah.v, bl[ct].v, z, 0, 0, 0);
      z = __builtin_amdgcn_mfma_f32_16x16x32_bf16(al.v, bh[ct].v, z, 0, 0, 0);
      acc[ct] = z;
    }
    // ---- fp32 epilogue: +b1 +ea-terms, relu, W2 dot; C row = q*4+reg ----
    float o0[4], o1[4];
#pragma unroll
    for (int reg = 0; reg < 4; reg++) {
      int pr = base + q * 4 + reg;
      float2 ea = make_float2(0.f, 0.f);
      if (pr < NV) ea = eat2[pr];
      float s0 = 0.f, s1 = 0.f;
#pragma unroll
      for (int ct = 0; ct < 4; ct++) {
        float h = acc[ct][reg] + b1v[ct] + ea.x * w16v[ct] + ea.y * w17v[ct];
        h = fmaxf(h, 0.f);
        s0 += h * w2a[ct];
        s1 += h * w2b[ct];
      }
      o0[reg] = s0; o1[reg] = s1;
    }
    // butterfly reduce across the 16 lanes sharing this row group
#pragma unroll
    for (int m = 1; m < 16; m <<= 1) {
#pragma unroll
      for (int reg = 0; reg < 4; reg++) {
        o0[reg] += __shfl_xor(o0[reg], m, 64);
        o1[reg] += __shfl_xor(o1[reg], m, 64);
      }
    }
    if (lo4 == 0) {
#pragma unroll
      for (int reg = 0; reg < 4; reg++) {
        int pr = base + q * 4 + reg;
        if (pr < NV) {
          float v0 = bias20 + o0[reg], v1 = bias21 + o1[reg];
          ((float2*)(out + 2 * (size_t)NV))[pr] = make_float2(
              1.f / (1.f + __expf(-v0)), 1.f / (1.f + __expf(-v1)));
        }
      }
    }
  }
}

static inline size_t al64(size_t v) { return (v + 63) & ~(size_t)63; }

extern "C" void kernel_launch(void* const* d_in, const int* in_sizes, int n_in,
                              void* d_out, int out_size, void* d_ws, size_t ws_size,
                              hipStream_t stream) {
  const float* x     = (const float*)d_in[0];
  const int*   edges = (const int*)d_in[1];
  const float* eattr = (const float*)d_in[2];
  const void*  labels= d_in[3];
  const float* Wg    = (const float*)d_in[4];
  const float* atts  = (const float*)d_in[5];
  const float* attd  = (const float*)d_in[6];
  const float* We    = (const float*)d_in[7];
  const float* atte  = (const float*)d_in[8];
  const float* bg    = (const float*)d_in[9];
  const float* W1    = (const float*)d_in[10];
  const float* b1    = (const float*)d_in[11];
  const float* W2    = (const float*)d_in[12];
  const float* b2    = (const float*)d_in[13];
  float* out = (float*)d_out;
  const int NV = out_size / 4;
  const int* src = edges;
  const int* dst = edges + NE;

  char* w = (char*)d_ws;
  float* xh    = (float*)w;   w += al64((size_t)NN * 64);
  uint2* bins  = (uint2*)w;   w += al64((size_t)NE * 8);
  float2* eat2 = (float2*)w;  w += al64((size_t)NV * 8);
  float* a_src = (float*)w;   w += al64((size_t)NN * 4);
  float* a_dst = (float*)w;   w += al64((size_t)NN * 4);
  int* labN    = (int*)w;     w += al64((size_t)NN * 4);
  int* blkcnt  = (int*)w;     w += al64((size_t)NBK * NCB * 4);
  int* total   = (int*)w;     w += al64((size_t)NBK * 4);
  int* bb      = (int*)w;     w += al64((size_t)(NBK + 1) * 4);
  int* cntc    = (int*)w;     w += al64((size_t)NCB * 4);
  int* offc    = (int*)w;     w += al64((size_t)(NCB + 1) * 4);
  float* c01   = (float*)w;   w += 64;
  int* flags   = (int*)w;     w += 64;

  kdetect<<<1, 256, 0, stream>>>((const unsigned char*)labels, flags);
  klab<<<(NN + 255) / 256, 256, 0, stream>>>(labels, flags, labN);
  kc01<<<1, 64, 0, stream>>>(We, atte, c01);
  knodeA<<<(NN + 255) / 256, 256, 0, stream>>>(x, Wg, atts, attd, a_src, a_dst);
  khist<<<NCB, 256, 0, stream>>>(src, dst, labN, blkcnt, cntc);
  kscanb<<<NBK, 256, 0, stream>>>(blkcnt, total);
  kscan<<<1, 256, 0, stream>>>(total, bb, NBK);
  kscan<<<1, 256, 0, stream>>>(cntc, offc, NCB);
  kscat<<<NCB, 256, 0, stream>>>(src, dst, eattr, labN, a_src, a_dst, c01, bb, blkcnt,
                                 offc, bins, out, eat2, NV);
  kagg<<<NBK, 512, 0, stream>>>(bins, bb, x, Wg, bg, xh);
  if (NV > 0)
    kmlp<<<2048, 256, 0, stream>>>(eat2, xh, W1, b1, W2, b2, out, NV);
}